// Round 18
// baseline (282.412 us; speedup 1.0000x reference)
//
#include <hip/hip_runtime.h>

#define DEV __device__ __forceinline__

typedef __bf16 bf16x8 __attribute__((ext_vector_type(8)));
typedef float f32x4 __attribute__((ext_vector_type(4)));

DEV unsigned short f2bf(float f) {
  __bf16 h = (__bf16)f;
  return __builtin_bit_cast(unsigned short, h);
}
DEV unsigned int cvtpk(float lo, float hi) {
  unsigned int r;
  asm("v_cvt_pk_bf16_f32 %0, %1, %2" : "=v"(r) : "v"(lo), "v"(hi));
  return r;
}

DEV void gload16(const void* g, void* l) {
  __builtin_amdgcn_global_load_lds(
      (const __attribute__((address_space(1))) unsigned int*)g,
      (__attribute__((address_space(3))) unsigned int*)l, 16, 0, 0);
}

template <int N>
DEV void vmw() { asm volatile("s_waitcnt vmcnt(%0)" :: "i"(N) : "memory"); }
DEV void barx() { asm volatile("s_barrier" ::: "memory"); }

// gelu via exp2: tanh(u) = 1 - 2/(exp2(u*2*log2e)+1)
DEV float gelu(float v) {
  const float u = 0.7978845608028654f * (v + 0.044715f * v * v * v);
  const float e = exp2f(u * 2.885390081777927f);
  return 0.5f * v * (2.f - 2.f / (e + 1.f));
}

// ---------- 64x64 transpose+convert (256-thread blocks) ----------
DEV void tconv64_body(const float* __restrict__ W, unsigned short* __restrict__ Wt,
                      int K, int N, int bx, int by, float* tile /* [64][65] */) {
  const int t = threadIdx.x;
  const int rr = t >> 4;
  const int cc = (t & 15) * 4;
#pragma unroll
  for (int it = 0; it < 4; it++) {
    float4 v = *reinterpret_cast<const float4*>(
        &W[(size_t)(by * 64 + it * 16 + rr) * N + bx * 64 + cc]);
    tile[(it * 16 + rr) * 65 + cc] = v.x;
    tile[(it * 16 + rr) * 65 + cc + 1] = v.y;
    tile[(it * 16 + rr) * 65 + cc + 2] = v.z;
    tile[(it * 16 + rr) * 65 + cc + 3] = v.w;
  }
  __syncthreads();
  const int nr = t >> 3;
  const int kc = (t & 7) * 8;
#pragma unroll
  for (int it = 0; it < 2; it++) {
    const int n = it * 32 + nr;
    uint4 o;
    o.x = cvtpk(tile[(kc + 0) * 65 + n], tile[(kc + 1) * 65 + n]);
    o.y = cvtpk(tile[(kc + 2) * 65 + n], tile[(kc + 3) * 65 + n]);
    o.z = cvtpk(tile[(kc + 4) * 65 + n], tile[(kc + 5) * 65 + n]);
    o.w = cvtpk(tile[(kc + 6) * 65 + n], tile[(kc + 7) * 65 + n]);
    *reinterpret_cast<uint4*>(&Wt[(size_t)(bx * 64 + n) * K + by * 64 + kc]) = o;
  }
}

// 512-thread variant: two tiles per block (tid = t&255, own LDS tile each);
// the single __syncthreads syncs both halves at the same point.
DEV void tconv64_pair(const float* __restrict__ W, unsigned short* __restrict__ Wt,
                      int K, int N, int bx, int by, float* tile, int tid) {
  const int rr = tid >> 4;
  const int cc = (tid & 15) * 4;
#pragma unroll
  for (int it = 0; it < 4; it++) {
    float4 v = *reinterpret_cast<const float4*>(
        &W[(size_t)(by * 64 + it * 16 + rr) * N + bx * 64 + cc]);
    tile[(it * 16 + rr) * 65 + cc] = v.x;
    tile[(it * 16 + rr) * 65 + cc + 1] = v.y;
    tile[(it * 16 + rr) * 65 + cc + 2] = v.z;
    tile[(it * 16 + rr) * 65 + cc + 3] = v.w;
  }
  __syncthreads();
  const int nr = tid >> 3;
  const int kc = (tid & 7) * 8;
#pragma unroll
  for (int it = 0; it < 2; it++) {
    const int n = it * 32 + nr;
    uint4 o;
    o.x = cvtpk(tile[(kc + 0) * 65 + n], tile[(kc + 1) * 65 + n]);
    o.y = cvtpk(tile[(kc + 2) * 65 + n], tile[(kc + 3) * 65 + n]);
    o.z = cvtpk(tile[(kc + 4) * 65 + n], tile[(kc + 5) * 65 + n]);
    o.w = cvtpk(tile[(kc + 6) * 65 + n], tile[(kc + 7) * 65 + n]);
    *reinterpret_cast<uint4*>(&Wt[(size_t)(bx * 64 + n) * K + by * 64 + kc]) = o;
  }
}

DEV void add_ln_body(const float* __restrict__ a, const float* b, float* x0_out,
                     unsigned short* __restrict__ y, const float* __restrict__ gam,
                     const float* __restrict__ bet, int row) {
  const int t = threadIdx.x;
  const int c = t * 4;
  const size_t base = (size_t)row * 1024 + c;
  float4 v = *reinterpret_cast<const float4*>(a + base);
  if (b) {
    float4 v2 = *reinterpret_cast<const float4*>(b + base);
    v.x += v2.x; v.y += v2.y; v.z += v2.z; v.w += v2.w;
  }
  if (x0_out) *reinterpret_cast<float4*>(x0_out + base) = v;
  float s = v.x + v.y + v.z + v.w;
  float sq = v.x * v.x + v.y * v.y + v.z * v.z + v.w * v.w;
#pragma unroll
  for (int o = 32; o > 0; o >>= 1) {
    s += __shfl_xor(s, o);
    sq += __shfl_xor(sq, o);
  }
  __shared__ float ps[4], pq[4];
  const int w = t >> 6;
  if ((t & 63) == 0) { ps[w] = s; pq[w] = sq; }
  __syncthreads();
  s = ps[0] + ps[1] + ps[2] + ps[3];
  sq = pq[0] + pq[1] + pq[2] + pq[3];
  const float mean = s * (1.f / 1024.f);
  const float var = sq * (1.f / 1024.f) - mean * mean;
  const float rstd = rsqrtf(var + 1e-5f);
  float4 gv = *reinterpret_cast<const float4*>(gam + c);
  float4 bv = *reinterpret_cast<const float4*>(bet + c);
  uint2 o2;
  o2.x = cvtpk((v.x - mean) * rstd * gv.x + bv.x, (v.y - mean) * rstd * gv.y + bv.y);
  o2.y = cvtpk((v.z - mean) * rstd * gv.z + bv.z, (v.w - mean) * rstd * gv.w + bv.w);
  *reinterpret_cast<uint2*>(y + base) = o2;
}

DEV void kvcast_body8(const float* __restrict__ p, const float* __restrict__ pe,
                      unsigned short* __restrict__ kvo, unsigned short* __restrict__ po,
                      int bid) {
  const size_t i = ((size_t)bid * 256 + threadIdx.x) * 8;
  float4 a0 = *reinterpret_cast<const float4*>(p + i);
  float4 a1 = *reinterpret_cast<const float4*>(p + i + 4);
  float4 b0 = *reinterpret_cast<const float4*>(pe + i);
  float4 b1 = *reinterpret_cast<const float4*>(pe + i + 4);
  uint4 kv, pp;
  kv.x = cvtpk(a0.x + b0.x, a0.y + b0.y);
  kv.y = cvtpk(a0.z + b0.z, a0.w + b0.w);
  kv.z = cvtpk(a1.x + b1.x, a1.y + b1.y);
  kv.w = cvtpk(a1.z + b1.z, a1.w + b1.w);
  pp.x = cvtpk(a0.x, a0.y);
  pp.y = cvtpk(a0.z, a0.w);
  pp.z = cvtpk(a1.x, a1.y);
  pp.w = cvtpk(a1.z, a1.w);
  *reinterpret_cast<uint4*>(kvo + i) = kv;
  *reinterpret_cast<uint4*>(po + i) = pp;
}

// ---------- prelude ----------
struct Pre {
  const float* caw[3]; unsigned short* cad[3];
  const float* state; const float* squery; float* stateF; unsigned short* lnB;
  const float* n1_g; const float* n1_b;
  const float* patches; const float* ppe; unsigned short* kvB; unsigned short* patB;
};
__global__ __launch_bounds__(256) void prelude_kernel(Pre p) {
  __shared__ __align__(16) float tile[64 * 65];
  const int bid = blockIdx.x;
  if (bid < 4096) {
    kvcast_body8(p.patches, p.ppe, p.kvB, p.patB, bid);
  } else if (bid < 4864) {
    const int i = bid - 4096;
    const int m = i >> 8, wi = i & 255;
    tconv64_body(p.caw[m], p.cad[m], 1024, 1024, wi & 15, wi >> 4, tile);
  } else {
    add_ln_body(p.state, p.squery, p.stateF, p.lnB, p.n1_g, p.n1_b, bid - 4864);
  }
}

__global__ __launch_bounds__(256) void add_ln_kernel(
    const float* __restrict__ a, const float* b, float* x0_out,
    unsigned short* __restrict__ y, const float* __restrict__ gam,
    const float* __restrict__ bet) {
  add_ln_body(a, b, x0_out, y, gam, bet, blockIdx.x);
}

// ---------- XCD swizzle helper (m204 bijective) ----------
DEV void xcd_swizzle(int gx, int gy, int& bx, int& by, int& bz) {
  const int gxy = gx * gy;
  const int nwg = gxy * gridDim.z;
  const int orig = (blockIdx.z * gy + blockIdx.y) * gx + blockIdx.x;
  const int q = nwg >> 3, r = nwg & 7;
  const int xcd = orig & 7;
  int wgid = (xcd < r ? xcd * (q + 1) : r * (q + 1) + (xcd - r) * q) + (orig >> 3);
  bz = wgid / gxy;
  wgid -= bz * gxy;
  if (gy >= gx) { by = wgid / gx; bx = wgid - by * gx; }
  else          { bx = wgid / gy; by = wgid - bx * gy; }
}

// ---------- GEMM core: 2-buffer single-barrier loop ----------
template <int BM, int BN>
DEV void gemm_core(const unsigned short* __restrict__ A,
                   const unsigned short* __restrict__ Bt,
                   unsigned short* As, unsigned short* Bs,
                   int brow, int bcol, int K, int lda, int koff,
                   f32x4 (&acc)[BM / 32][BN / 32]) {
  constexpr int WM = BM / 32, WN = BN / 32;
  const int t = threadIdx.x;
  const int lane = t & 63, w = t >> 6;
  const int wr = w >> 1, wc = w & 1;
  const int g = lane >> 4, lr = lane & 15;
  const int srow = lane >> 2, scol = (lane & 3) * 8;

  auto stage = [&](int buf, int k0) {
#pragma unroll
    for (int i = 0; i < BM / 64; i++) {
      const int r0 = (i * 4 + w) * 16;
      gload16(A + (size_t)(brow + r0 + srow) * lda + koff + k0 + scol,
              &As[buf * BM * 32 + r0 * 32]);
    }
#pragma unroll
    for (int i = 0; i < BN / 64; i++) {
      const int r0 = (i * 4 + w) * 16;
      gload16(Bt + (size_t)(bcol + r0 + srow) * lda + koff + k0 + scol,
              &Bs[buf * BN * 32 + r0 * 32]);
    }
  };

  stage(0, 0);
  const int nk = K / 32;
  int cur = 0;
  for (int kt = 0; kt < nk; kt++) {
    __syncthreads();
    if (kt + 1 < nk) stage(cur ^ 1, (kt + 1) * 32);
    bf16x8 af[WM], bfr[WN];
#pragma unroll
    for (int m = 0; m < WM; m++)
      af[m] = *reinterpret_cast<const bf16x8*>(
          &As[cur * BM * 32 + (wr * (BM / 2) + m * 16 + lr) * 32 + g * 8]);
#pragma unroll
    for (int n = 0; n < WN; n++)
      bfr[n] = *reinterpret_cast<const bf16x8*>(
          &Bs[cur * BN * 32 + (wc * (BN / 2) + n * 16 + lr) * 32 + g * 8]);
    __builtin_amdgcn_s_setprio(1);
#pragma unroll
    for (int m = 0; m < WM; m++)
#pragma unroll
      for (int n = 0; n < WN; n++)
        acc[m][n] = __builtin_amdgcn_mfma_f32_16x16x32_bf16(af[m], bfr[n], acc[m][n], 0, 0, 0);
    __builtin_amdgcn_s_setprio(0);
    cur ^= 1;
  }
}

// ---------- transposed-V epilogue (128-row tiles, 256-thread kernels) ----------
template <int BM, int BN>
DEV void epilogue_vT(f32x4 (&acc)[BM / 32][BN / 32], unsigned short* smem,
                     unsigned short* __restrict__ vT, const float* __restrict__ bias,
                     int brow, int bcol, int vcol0, int vNk, int rpb) {
  constexpr int WM = BM / 32, WN = BN / 32;
  constexpr int LDT = 136;
  const int t = threadIdx.x, lane = t & 63, w = t >> 6;
  const int wr = w >> 1, wc = w & 1;
  const int g = lane >> 4, lr = lane & 15;
  __syncthreads();
#pragma unroll
  for (int m = 0; m < WM; m++) {
    const int row0 = wr * (BM / 2) + m * 16 + g * 4;
#pragma unroll
    for (int n = 0; n < WN; n++) {
      const int cc = wc * (BN / 2) + n * 16 + lr;
      const float bv = bias[bcol + cc];
      uint2 pk;
      pk.x = cvtpk(acc[m][n][0] + bv, acc[m][n][1] + bv);
      pk.y = cvtpk(acc[m][n][2] + bv, acc[m][n][3] + bv);
      *reinterpret_cast<uint2*>(&smem[cc * LDT + row0]) = pk;
    }
  }
  __syncthreads();
  const int b = brow / rpb;
  const int kvb = brow % rpb;
  constexpr int ITERS = BM * BN / (256 * 8);
#pragma unroll
  for (int it = 0; it < ITERS; it++) {
    const int idx = it * 256 + t;
    const int cc = idx / (BM / 8);
    const int ch = idx % (BM / 8);
    const int dg = bcol + cc - vcol0;
    const int h = dg >> 6, d = dg & 63;
    uint4 v = *reinterpret_cast<uint4*>(&smem[cc * LDT + ch * 8]);
    *reinterpret_cast<uint4*>(
        &vT[((size_t)(b * 16 + h) * 64 + d) * vNk + kvb + ch * 8]) = v;
  }
}

// ---------- GEMM with epilogues ----------
template <int EPI, int BM, int BN>
__global__ __launch_bounds__(256) void gemm_kernel(
    const unsigned short* __restrict__ A, const unsigned short* __restrict__ Bt,
    const float* __restrict__ bias, const float* resid,
    const float* __restrict__ ls, void* outp, int M, int N, int K, int lda) {
  constexpr int WM = BM / 32;
  constexpr int WN = BN / 32;
  __shared__ __align__(16) unsigned short smem[2 * BM * 32 + 2 * BN * 32];
  unsigned short* As = smem;
  unsigned short* Bs = smem + 2 * BM * 32;
  const int t = threadIdx.x;
  const int lane = t & 63, w = t >> 6;
  const int wr = w >> 1, wc = w & 1;
  const int g = lane >> 4, lr = lane & 15;

  int bx, by, bz;
  xcd_swizzle(gridDim.x, gridDim.y, bx, by, bz);
  const int brow = by * BM, bcol = bx * BN;

  f32x4 acc[WM][WN] = {};
  gemm_core<BM, BN>(A, Bt, As, Bs, brow, bcol, K, lda, bz * K, acc);

#pragma unroll
  for (int m = 0; m < WM; m++) {
    const int row0 = brow + wr * (BM / 2) + m * 16 + g * 4;
#pragma unroll
    for (int n = 0; n < WN; n++) {
      const int col = bcol + wc * (BN / 2) + n * 16 + lr;
      const float bv = (EPI == 4) ? 0.f : bias[col];
#pragma unroll
      for (int r = 0; r < 4; r++) {
        const float v = acc[m][n][r] + bv;
        const size_t idx = (size_t)(row0 + r) * N + col;
        if (EPI == 0) {
          ((unsigned short*)outp)[idx] = f2bf(v);
        } else if (EPI == 2) {
          ((float*)outp)[idx] = resid[idx] + v * ls[col];
        } else if (EPI == 3) {
          ((unsigned short*)outp)[idx] = f2bf(gelu(v));
        } else {
          ((float*)outp)[(size_t)bz * M * N + idx] = v;
        }
      }
    }
  }
}

// ---------- MFMA quadrant phase (compile-time indices -> no scratch) ----------
template <int QM, int QN>
DEV void mm_phase(f32x4 (&acc)[8][4], const bf16x8 (&a)[4][2], const bf16x8 (&b)[2][2]) {
  __builtin_amdgcn_s_setprio(1);
#pragma unroll
  for (int mi = 0; mi < 4; mi++)
#pragma unroll
    for (int ni = 0; ni < 2; ni++)
#pragma unroll
      for (int kk = 0; kk < 2; kk++)
        acc[QM * 4 + mi][QN * 2 + ni] = __builtin_amdgcn_mfma_f32_16x16x32_bf16(
            a[mi][kk], b[ni][kk], acc[QM * 4 + mi][QN * 2 + ni], 0, 0, 0);
  __builtin_amdgcn_s_setprio(0);
}

// ---------- 8-phase 256x256 packed gemm3 (q/k/v projections) ----------
// 512 thr / 8 waves (wr=w>>2, wc=w&3); wave tile 128x64; BK=64; LDS [2][256][64] x2.
// Per K-tile T (buf=T&1), 4 phases = C-quadrants (0,0),(0,1),(1,1),(1,0).
// Region-free schedule (stage targets freed regions; barriers separate):
//   q=0: stage B-h0(T+1)->buf^1 (B-h0(T-1) freed @ T-1 q=3... last read q=0 of T-1)
//   q=1: stage A-h1(T+1)->buf^1 (A-h1(T-1) freed @ T-1 q=2)
//   q=2: stage A-h0(T+2)->buf   (A-h0(T)   freed @ q=0)
//   q=3: stage B-h1(T+2)->buf   (B-h1(T)   freed @ q=1)
// Certification: vmcnt(4) at q=3 (allows the 2 tile-T+2 stages in flight) covers
// all halves of tile T+1; vmcnt(0) only when T+2 >= nk (no stages behind).
// LDS swizzle (T2, m201 both-sides): linear dest; source col (t&7)^((t>>3)&7);
// read addr XOR row&7 into the 16B-block bits -> 2-way banks (free).
struct G8P {
  const unsigned short* A[3]; const unsigned short* Bt[3];
  const float* bias[3]; unsigned short* out[3]; int ecum[3];
  unsigned short* vT; int vNk; int rpb;
  const float* wp; unsigned short* wpt;
  const float* saw[4]; unsigned short* sad[4];
  const float* bq; const float* bk; const float* bv; float* bqkv;
};
__global__ __launch_bounds__(512, 2) void gemm8p_kernel(G8P p, int N, int K) {
  constexpr int NG = 288;
  __shared__ __align__(16) unsigned short smem[65536];  // 128 KiB
  const int bid = blockIdx.x;
  const int t = threadIdx.x;

  if (bid >= NG) {  // ---- aux tail: paired weight transposes + cat3 ----
    int i = bid - NG;
    const int tid = t & 255, sel = t >> 8;
    float* tile = reinterpret_cast<float*>(smem) + sel * 4224;
    if (i < 128) {
      const int ti = i * 2 + sel;
      tconv64_pair(p.wp, p.wpt, 1024, 1024, ti & 15, ti >> 4, tile, tid);
    } else if (i < 640) {
      const int ti = (i - 128) * 2 + sel;
      const int m = ti >> 8, wi = ti & 255;
      tconv64_pair(p.saw[m], p.sad[m], 1024, 1024, wi & 15, wi >> 4, tile, tid);
    } else {
      const int j = (i - 640) * 512 + t;
      if (j < 3072)
        p.bqkv[j] = j < 1024 ? p.bq[j] : (j < 2048 ? p.bk[j - 1024] : p.bv[j - 2048]);
    }
    return;
  }

  // ---- GEMM range ----
  const int wgid = (bid & 7) * 36 + (bid >> 3);  // bijective XCD swizzle (288 = 8*36)
  const int bx = wgid & 3, by = wgid >> 2;
  const int s = (by >= p.ecum[0]) + (by >= p.ecum[1]);
  const int byloc = by - (s ? p.ecum[s - 1] : 0);
  const unsigned short* A = p.A[s];
  const unsigned short* Bt = p.Bt[s];
  const float* bias = p.bias[s];
  const int brow = byloc * 256, bcol = bx * 256;

  unsigned short* AsL = smem;            // [2][256*64]
  unsigned short* BsL = smem + 32768;

  const int w = t >> 6, lane = t & 63;
  const int wr = w >> 2, wc = w & 3;
  const int g = lane >> 4, lr = lane & 15;
  const int sr8 = t >> 3;
  const int scx = (((t & 7) ^ ((t >> 3) & 7)) << 3);  // swizzled source col (elems)
  const int wvb = w << 3;

  auto stageA = [&](int buf, int T, int h) {
#pragma unroll
    for (int i = 0; i < 2; i++)
      gload16(A + (size_t)(brow + h * 128 + i * 64 + sr8) * K + T * 64 + scx,
              &AsL[buf * 16384 + (h * 128 + i * 64 + wvb) * 64]);
  };
  auto stageB = [&](int buf, int T, int h) {
#pragma unroll
    for (int i = 0; i < 2; i++)
      gload16(Bt + (size_t)(bcol + h * 128 + i * 64 + sr8) * K + T * 64 + scx,
              &BsL[buf * 16384 + (h * 128 + i * 64 + wvb) * 64]);
  };

  bf16x8 a[4][2], b0[2][2], b1[2][2];
  auto loadA = [&](int buf, int qm) {
#pragma unroll
    for (int mi = 0; mi < 4; mi++) {
      const int row = qm * 128 + wr * 64 + mi * 16 + lr;
#pragma unroll
      for (int kk = 0; kk < 2; kk++)
        a[mi][kk] = *reinterpret_cast<const bf16x8*>(
            &AsL[buf * 16384 + row * 64 + ((((kk << 2) + g) ^ (row & 7)) << 3)]);
    }
  };
  auto loadB = [&](int buf, int qn, bf16x8 (&b)[2][2]) {
#pragma unroll
    for (int ni = 0; ni < 2; ni++) {
      const int row = qn * 128 + wc * 32 + ni * 16 + lr;
#pragma unroll
      for (int kk = 0; kk < 2; kk++)
        b[ni][kk] = *reinterpret_cast<const bf16x8*>(
            &BsL[buf * 16384 + row * 64 + ((((kk << 2) + g) ^ (row & 7)) << 3)]);
    }
  };

  f32x4 acc[8][4] = {};

  // prologue: tile0 all halves; tile1 A-h0, B-h1 (its B-h0/A-h1 staged in tile0)
  stageA(0, 0, 0); stageB(0, 0, 0); stageA(0, 0, 1); stageB(0, 0, 1);
  stageA(1, 1, 0); stageB(1, 1, 1);
  vmw<4>();
  barx();

  const int nk = K >> 6;  // 16
  for (int T = 0; T < nk; T++) {
    const int buf = T & 1;
    // q=0: quadrant (0,0)
    loadA(buf, 0); loadB(buf, 0, b0);
    if (T + 1 < nk) stageB(buf ^ 1, T + 1, 0);
    barx();
    mm_phase<0, 0>(acc, a, b0);
    barx();
    // q=1: (0,1)
    loadB(buf, 1, b1);
    if (T + 1 < nk) stageA(buf ^ 1, T + 1, 1);
    barx();
    mm_phase<0, 1>(acc, a, b1);
    barx();
    // q=2: (1,1)
    loadA(buf, 1);
    if (T + 2 < nk) stageA(buf, T + 2, 0);
    barx();
    mm_phase<1, 1>(acc, a, b1);
    barx();
    // q=3: (1,0) — reuse b0; certify tile T+1
    if (T + 2 < nk) { stageB(buf, T + 2, 1); vmw<4>(); } else { vmw<0>(); }
    barx();
    mm_phase<1, 0>(acc, a, b0);
    barx();
  }
  vmw<0>();
  barx();

  if (s == 2) {  // V segment: transposed write, two 128-row passes
    const int b_ = brow / p.rpb;
    const int kvb = brow % p.rpb;
#pragma unroll
    for (int h2 = 0; h2 < 2; h2++) {
      if (h2) barx();
#pragma unroll
      for (int mi = 0; mi < 4; mi++) {
        const int m = h2 * 4 + mi;
        const int rowL = wr * 64 + mi * 16 + g * 4;
#pragma unroll
        for (int n = 0; n < 4; n++) {
          const int cc = (n >> 1) * 128 + wc * 32 + (n & 1) * 16 + lr;
          const float bv = bias[bcol + cc];
          uint2 pk;
          pk.x = cvtpk(acc[m][n][0] + bv, acc[m][n][1] + bv);
          pk.y = cvtpk(acc[m][n][2] + bv, acc[m][n][3] + bv);
          *reinterpret_cast<uint2*>(&smem[cc * 136 + rowL]) = pk;
        }
      }
      barx();
#pragma unroll
      for (int it = 0; it < 8; it++) {
        const int idx = it * 512 + t;
        const int cc = idx >> 4, ch = idx & 15;
        const int dg = bcol + cc;
        const int hh = dg >> 6, dd = dg & 63;
        uint4 v = *reinterpret_cast<uint4*>(&smem[cc * 136 + ch * 8]);
        *reinterpret_cast<uint4*>(
            &p.vT[((size_t)(b_ * 16 + hh) * 64 + dd) * p.vNk + kvb + h2 * 128 + ch * 8]) = v;
      }
    }
    return;
  }
  unsigned short* outp = p.out[s];
#pragma unroll
  for (int m = 0; m < 8; m++) {
    const int row0 = brow + (m >> 2) * 128 + wr * 64 + (m & 3) * 16 + g * 4;
#pragma unroll
    for (int n = 0; n < 4; n++) {
      const int col = bcol + (n >> 1) * 128 + wc * 32 + (n & 1) * 16 + lr;
      const float bv = bias[col];
#pragma unroll
      for (int r = 0; r < 4; r++)
        outp[(size_t)(row0 + r) * N + col] = f2bf(acc[m][n][r] + bv);
    }
  }
}

// ---------- packed saQKV + w1/w2 transpose tail ----------
struct G5X {
  const unsigned short* A; const unsigned short* Bt;
  const float* bias; unsigned short* out;
  unsigned short* vT; int vcol0; int vNk; int rpb;
  const float* w1; unsigned short* w1t;
  const float* w2; unsigned short* w2t;
};
__global__ __launch_bounds__(256) void gemm5x_kernel(G5X p, int M, int N, int K) {
  constexpr int BM = 128, BN = 64, WM = BM / 32, WN = BN / 32;
  constexpr int STG = 2 * BM * 32 + 2 * BN * 32;
  __shared__ __align__(16) unsigned short smem[STG];
  constexpr int NG = 768;
  const int bid = blockIdx.x;
  const int t = threadIdx.x;

  if (bid >= NG) {
    float* tile = reinterpret_cast<float*>(smem);
    int i = bid - NG;
    if (i < 1024) {
      tconv64_body(p.w1, p.w1t, 1024, 4096, i & 63, i >> 6, tile);
    } else {
      i -= 1024;
      tconv64_body(p.w2, p.w2t, 4096, 1024, i & 15, i >> 4, tile);
    }
    return;
  }

  unsigned short* As = smem;
  unsigned short* Bs = smem + 2 * BM * 32;
  const int lane = t & 63, w = t >> 6;
  const int wr = w >> 1, wc = w & 1;
  const int g = lane >> 4, lr = lane & 15;
  const int wgid = (bid & 7) * (NG >> 3) + (bid >> 3);
  const int bx = wgid >> 4, by = wgid & 15;
  const int brow = by * BM, bcol = bx * BN;

  f32x4 acc[WM][WN] = {};
  gemm_core<BM, BN>(p.A, p.Bt, As, Bs, brow, bcol, K, K, 0, acc);

  if (bcol >= p.vcol0) {
    epilogue_vT<BM, BN>(acc, smem, p.vT, p.bias, brow, bcol, p.vcol0, p.vNk, p.rpb);
    return;
  }
#pragma unroll
  for (int m = 0; m < WM; m++) {
    const int row0 = brow + wr * (BM / 2) + m * 16 + g * 4;
#pragma unroll
    for (int n = 0; n < WN; n++) {
      const int col = bcol + wc * (BN / 2) + n * 16 + lr;
      const float bv = p.bias[col];
#pragma unroll
      for (int r = 0; r < 4; r++)
        p.out[(size_t)(row0 + r) * N + col] = f2bf(acc[m][n][r] + bv);
    }
  }
}

// ---------- split-K reduce + epilogue ----------
__global__ __launch_bounds__(256) void splitk_red_kernel(
    const float* __restrict__ p, const float* __restrict__ bias,
    const float* __restrict__ resid, const float* __restrict__ ls,
    float* __restrict__ out) {
  const size_t i = ((size_t)blockIdx.x * 256 + threadIdx.x) * 4;
  const int c = (int)(i & 1023);
  float4 a = *reinterpret_cast<const float4*>(p + i);
  float4 b = *reinterpret_cast<const float4*>(p + 2048ull * 1024 + i);
  float4 rv = *reinterpret_cast<const float4*>(resid + i);
  float4 bb = *reinterpret_cast<const float4*>(bias + c);
  float4 lv = *reinterpret_cast<const float4*>(ls + c);
  float4 o;
  o.x = rv.x + (a.x + b.x + bb.x) * lv.x;
  o.y = rv.y + (a.y + b.y + bb.y) * lv.y;
  o.z = rv.z + (a.z + b.z + bb.z) * lv.z;
  o.w = rv.w + (a.w + b.w + bb.w) * lv.w;
  *reinterpret_cast<float4*>(out + i) = o;
}

// ---------- flash attention (R17 structure) ----------
template <int SPLIT>
__global__ __launch_bounds__(512) void attn_kernel(
    const unsigned short* __restrict__ Q, const unsigned short* __restrict__ Kp,
    const unsigned short* __restrict__ vT, unsigned short* __restrict__ O,
    float* __restrict__ opart, float* __restrict__ mlbuf,
    int RSq, int RSk, int Nq, int NkTot, int NkL, float k2) {
  __shared__ __align__(16) unsigned short Ks[128 * 72];
  __shared__ __align__(16) unsigned short Vs[64 * 136];
  __shared__ __align__(16) unsigned short Ps[128 * 136];
  const int t = threadIdx.x, lane = t & 63, w = t >> 6;
  const int qt = blockIdx.y, h = blockIdx.x & 15, b = blockIdx.x >> 4;
  const int z = blockIdx.z;
  const int kvbase = z * NkL;
  const int g = lane >> 4, lr = lane & 15;
  const int ksrow = t >> 2, kscol = (t & 3) * 16;
  const int vsrow = t >> 3, vscol = (t & 7) * 16;

  uint4 qr[2];
  {
    const unsigned short* qp = Q + (size_t)(b * Nq + qt * 128 + w * 16 + lr) * RSq + h * 64 + g * 8;
    qr[0] = *reinterpret_cast<const uint4*>(qp);
    qr[1] = *reinterpret_cast<const uint4*>(qp + 32);
  }
  float m_i = -1e30f, l_i = 0.f;
  f32x4 acc_o[4] = {};

  auto kaddr = [&](int kv0) {
    return reinterpret_cast<const uint4*>(
        Kp + (size_t)(b * NkTot + kvbase + kv0 + ksrow) * RSk + h * 64 + kscol);
  };
  auto vaddr = [&](int kv0) {
    return reinterpret_cast<const uint4*>(
        vT + ((size_t)(b * 16 + h) * 64 + vsrow) * NkTot + kvbase + kv0 + vscol);
  };

  uint4 kr0 = kaddr(0)[0], kr1 = kaddr(0)[1];
  uint4 vr0 = vaddr(0)[0], vr1 = vaddr(0)[1];

  for (int kv0 = 0; kv0 < NkL; kv0 += 128) {
    *reinterpret_cast<uint4*>(&Ks[ksrow * 72 + kscol]) = kr0;
    *reinterpret_cast<uint4*>(&Ks[ksrow * 72 + kscol + 8]) = kr1;
    *reinterpret_cast<uint4*>(&Vs[vsrow * 136 + vscol]) = vr0;
    *reinterpret_cast<uint4*>(&Vs[vsrow * 136 + vscol + 8]) = vr1;
    __syncthreads();
    if (kv0 + 128 < NkL) {
      kr0 = kaddr(kv0 + 128)[0]; kr1 = kaddr(kv0 + 128)[1];
      vr0 = vaddr(kv0 + 128)[0]; vr1 = vaddr(kv0 + 128)[1];
    }

    f32x4 accs[8] = {};
    __builtin_amdgcn_s_setprio(1);
#pragma unroll
    for (int d0 = 0; d0 < 64; d0 += 32) {
      bf16x8 qf = __builtin_bit_cast(bf16x8, qr[d0 >> 5]);
#pragma unroll
      for (int m = 0; m < 8; m++) {
        bf16x8 kf = *reinterpret_cast<const bf16x8*>(&Ks[(m * 16 + lr) * 72 + d0 + g * 8]);
        accs[m] = __builtin_amdgcn_mfma_f32_16x16x32_bf16(kf, qf, accs[m], 0, 0, 0);
      }
    }
    __builtin_amdgcn_s_setprio(0);
    float pmax = -1e30f;
#pragma unroll
    for (int m = 0; m < 8; m++)
#pragma unroll
      for (int r = 0; r < 4; r++) pmax = fmaxf(pmax, accs[m][r]);
    pmax = fmaxf(pmax, __shfl_xor(pmax, 16));
    pmax = fmaxf(pmax, __shfl_xor(pmax, 32));
    const float pm2 = pmax * k2;
    if (!__all(pm2 <= m_i + 8.f)) {
      const float m_new = fmaxf(m_i, pm2);
      const float corr = exp2f(m_i - m_new);
      m_i = m_new;
      l_i *= corr;
#pragma unroll
      for (int r = 0; r < 4; r++) {
        const float cf = __shfl(corr, g * 4 + r);
#pragma unroll
        for (int n = 0; n < 4; n++) acc_o[n][r] *= cf;
      }
    }
    float psum = 0.f;
#pragma unroll
    for (int m = 0; m < 8; m++) {
      float p0 = exp2f(fmaf(accs[m][0], k2, -m_i));
      float p1 = exp2f(fmaf(accs[m][1], k2, -m_i));
      float p2 = exp2f(fmaf(accs[m][2], k2, -m_i));
      float p3 = exp2f(fmaf(accs[m][3], k2, -m_i));
      psum += p0 + p1 + p2 + p3;
      uint2 pk;
      pk.x = cvtpk(p0, p1);
      pk.y = cvtpk(p2, p3);
      *reinterpret_cast<uint2*>(&Ps[(w * 16 + lr) * 136 + m * 16 + g * 4]) = pk;
    }
    psum += __shfl_xor(psum, 16);
    psum += __shfl_xor(psum, 32);
    l_i += psum;
    __builtin_amdgcn_s_setprio(1);
#pragma unroll
    for (int ks = 0; ks < 4; ks++) {
      bf16x8 pf = *reinterpret_cast<const bf16x8*>(&Ps[(w * 16 + lr) * 136 + ks * 32 + g * 8]);
#pragma unroll
      for (int n = 0; n < 4; n++) {
        bf16x8 vf = *reinterpret_cast<const bf16x8*>(&Vs[(n * 16 + lr) * 136 + ks * 32 + g * 8]);
        acc_o[n] = __builtin_amdgcn_mfma_f32_16x16x32_bf16(pf, vf, acc_o[n], 0, 0, 0);
      }
    }
    __builtin_amdgcn_s_setprio(0);
    __syncthreads();
  }

  if (SPLIT) {
    const int R0 = ((b * 16 + h) << 9) + qt * 128 + w * 16;
    if (lane < 16) {
      mlbuf[(size_t)(R0 + lr) * 4 + z * 2] = m_i;
      mlbuf[(size_t)(R0 + lr) * 4 + z * 2 + 1] = l_i;
    }
#pragma unroll
    for (int r = 0; r < 4; r++) {
      const int R = R0 + g * 4 + r;
#pragma unroll
      for (int n = 0; n < 4; n++)
        opart[((size_t)z * 32768 + R) * 64 + n * 16 + lr] = acc_o[n][r];
    }
  } else {
#pragma unroll
    for (int r = 0; r < 4; r++) {
      const float li = __shfl(l_i, g * 4 + r);
      const float inv = 1.f / li;
      const int qrow = qt * 128 + w * 16 + g * 4 + r;
#pragma unroll
      for (int n = 0; n < 4; n++)
        O[(size_t)(b * Nq + qrow) * 1024 + h * 64 + n * 16 + lr] = f2bf(acc_o[n][r] * inv);
    }
  }
}

__global__ __launch_bounds__(256) void attn_combine_kernel(
    const float* __restrict__ opart, const float* __restrict__ mlbuf,
    unsigned short* __restrict__ O) {
  const int idx = blockIdx.x * 256 + threadIdx.x;
  const int R = idx >> 4;
  const int dq = (idx & 15) * 4;
  const float m1 = mlbuf[R * 4 + 0], l1 = mlbuf[R * 4 + 1];
  const float m2 = mlbuf[R * 4 + 2], l2 = mlbuf[R * 4 + 3];
  const float mm = fmaxf(m1, m2);
  const float e1 = exp2f(m1 - mm), e2 = exp2f(m2 - mm);
  const float inv = 1.f / (e1 * l1 + e2 * l2);
  float4 a = *reinterpret_cast<const float4*>(&opart[(size_t)R * 64 + dq]);
  float4 b = *reinterpret_cast<const float4*>(&opart[(size_t)(R + 32768) * 64 + dq]);
  const int bb = R >> 13, h = (R >> 9) & 15, q = R & 511;
  uint2 pk;
  pk.x = cvtpk((e1 * a.x + e2 * b.x) * inv, (e1 * a.y + e2 * b.y) * inv);
  pk.y = cvtpk((e1 * a.z + e2 * b.z) * inv, (e1 * a.w + e2 * b.w) * inv);
  *reinterpret_cast<uint2*>(O + ((size_t)(bb * 512 + q)) * 1024 + h * 64 + dq) = pk;
}

extern "C" void kernel_launch(void* const* d_in, const int* in_sizes, int n_in,
                              void* d_out, int out_size, void* d_ws, size_t ws_size,
                              hipStream_t stream) {
  const float* state = (const float*)d_in[0];
  const float* patches = (const float*)d_in[1];
  const float* ppe = (const float*)d_in[2];
  const float* squery = (const float*)d_in[3];
  const float* ca_wq = (const float*)d_in[4];
  const float* ca_bq = (const float*)d_in[5];
  const float* ca_wk = (const float*)d_in[6];
  const float* ca_bk = (const float*)d_in[7];
  const float* ca_wv = (const float*)d_in[8];
  const float* ca_bv = (const float*)d_in[9];
  const float* ca_wp = (const float*)d_in[10];
  const float* ca_bp = (const float*)d_in[11];
  const float* sa_wq = (const float*)d_in[12];
  const float* sa_bq = (const float*)d_in[13];
  const float* sa_wk = (const float*)d_in[14];
  const float* sa_bk = (const float*)d_in[15];
  const float* sa_wv = (const float*)d_in[16];
  const float* sa_bv = (const float*)d_in[17];
  const float* sa_wp = (const float*)d_in[18];
  const float* sa_bp = (const float*)d_in[19];
  const float* w1 = (const float*)d_in[20];
  const float* b1 = (const float*)d_in[21];
  const float* w2 = (const float*)d_in[22];
  const float* b2 = (const float*)d_in[23];
  const float* n1_g = (const float*)d_in[24];
  const float* n1_b = (const float*)d_in[25];
  const float* ls1 = (const float*)d_in[26];
  const float* n2_g = (const float*)d_in[27];
  const float* n2_b = (const float*)d_in[28];
  const float* ls2 = (const float*)d_in[29];
  const float* n3_g = (const float*)d_in[30];
  const float* n3_b = (const float*)d_in[31];
  const float* ls3 = (const float*)d_in[32];

  char* wsp = (char*)d_ws;
  auto alloc = [&](size_t bytes) {
    void* p = (void*)wsp;
    wsp += (bytes + 255) & ~(size_t)255;
    return p;
  };
  float* stateF = (float*)alloc(2048ull * 1024 * 4);
  unsigned short* lnB = (unsigned short*)alloc(2048ull * 1024 * 2);
  unsigned short* kvB = (unsigned short*)alloc(8192ull * 1024 * 2);
  unsigned short* patB = (unsigned short*)alloc(8192ull * 1024 * 2);
  unsigned short* qB = (unsigned short*)alloc(2048ull * 1024 * 2);
  unsigned short* kB = (unsigned short*)alloc(8192ull * 1024 * 2);
  unsigned short* vB = (unsigned short*)alloc(8192ull * 1024 * 2);
  unsigned short* oB = (unsigned short*)alloc(2048ull * 1024 * 2);
  unsigned short* hB = kvB;      // kvB dead after gemm8p
  unsigned short* qkvB = kB;     // kB dead after cross attention
  unsigned short* vTc = vB;      // cross V written transposed directly here
  unsigned short* vTs = qB;      // qB dead after cross attention
  float* opart = (float*)patB;   // patB dead after gemm8p
  float* mlp2p = (float*)patB;   // reused again at MLP2
  unsigned short* ca_wqt = (unsigned short*)alloc(1024ull * 1024 * 2);
  unsigned short* ca_wkt = (unsigned short*)alloc(1024ull * 1024 * 2);
  unsigned short* ca_wvt = (unsigned short*)alloc(1024ull * 1024 * 2);
  unsigned short* ca_wpt = (unsigned short*)alloc(1024ull * 1024 * 2);
  unsigned short* sa_wqkvt = (unsigned short*)alloc(3072ull * 1024 * 2);
  unsigned short* sa_wpt = (unsigned short*)alloc(1024ull * 1024 * 2);
  unsigned short* w1t = (unsigned short*)alloc(4096ull * 1024 * 2);
  unsigned short* w2t = (unsigned short*)alloc(4096ull * 1024 * 2);
  float* sa_bqkv = (float*)alloc(3072 * 4);
  float* mlbuf = (float*)alloc(32768ull * 4 * 4);

  // ---- prelude ----
  Pre pre;
  pre.caw[0] = ca_wq; pre.cad[0] = ca_wqt;
  pre.caw[1] = ca_wk; pre.cad[1] = ca_wkt;
  pre.caw[2] = ca_wv; pre.cad[2] = ca_wvt;
  pre.state = state; pre.squery = squery; pre.stateF = stateF; pre.lnB = lnB;
  pre.n1_g = n1_g; pre.n1_b = n1_b;
  pre.patches = patches; pre.ppe = ppe; pre.kvB = kvB; pre.patB = patB;
  prelude_kernel<<<6912, 256, 0, stream>>>(pre);

  const float k2 = 0.125f * 1.4426950408889634f;  // 64^-0.5 * log2(e)

  // packed 8-phase gemm3: q/k/v projections (288 blocks 256^2) + aux tail
  G8P g8;
  g8.A[0] = lnB;  g8.Bt[0] = ca_wqt; g8.bias[0] = ca_bq; g8.out[0] = qB;      g8.ecum[0] = 8;
  g8.A[1] = kvB;  g8.Bt[1] = ca_wkt; g8.bias[1] = ca_bk; g8.out[1] = kB;      g8.ecum[1] = 40;
  g8.A[2] = patB; g8.Bt[2] = ca_wvt; g8.bias[2] = ca_bv; g8.out[2] = nullptr; g8.ecum[2] = 72;
  g8.vT = vTc; g8.vNk = 2048; g8.rpb = 2048;
  g8.wp = ca_wp; g8.wpt = ca_wpt;
  g8.saw[0] = sa_wq; g8.sad[0] = sa_wqkvt;
  g8.saw[1] = sa_wk; g8.sad[1] = sa_wqkvt + 1024ull * 1024;
  g8.saw[2] = sa_wv; g8.sad[2] = sa_wqkvt + 2048ull * 1024;
  g8.saw[3] = sa_wp; g8.sad[3] = sa_wpt;
  g8.bq = sa_bq; g8.bk = sa_bk; g8.bv = sa_bv; g8.bqkv = sa_bqkv;
  gemm8p_kernel<<<934, 512, 0, stream>>>(g8, 1024, 1024);
  // cross attention: 2-way KV split + combine
  attn_kernel<1><<<dim3(64, 4, 2), 512, 0, stream>>>(
      qB, kB, vTc, nullptr, opart, mlbuf, 1024, 1024, 512, 2048, 1024, k2);
  attn_combine_kernel<<<2048, 256, 0, stream>>>(opart, mlbuf, oB);
  gemm_kernel<2, 64, 64><<<dim3(16, 32), 256, 0, stream>>>(oB, ca_wpt, ca_bp, stateF, ls1, stateF, 2048, 1024, 1024, 1024);

  // self-attn
  add_ln_kernel<<<2048, 256, 0, stream>>>(stateF, nullptr, nullptr, lnB, n2_g, n2_b);
  G5X g5;
  g5.A = lnB; g5.Bt = sa_wqkvt; g5.bias = sa_bqkv; g5.out = qkvB;
  g5.vT = vTs; g5.vcol0 = 2048; g5.vNk = 512; g5.rpb = 512;
  g5.w1 = w1; g5.w1t = w1t; g5.w2 = w2; g5.w2t = w2t;
  gemm5x_kernel<<<2816, 256, 0, stream>>>(g5, 2048, 3072, 1024);
  attn_kernel<0><<<dim3(64, 4, 1), 512, 0, stream>>>(
      qkvB, qkvB + 1024, vTs, oB, nullptr, nullptr, 3072, 3072, 512, 512, 512, k2);
  gemm_kernel<2, 64, 64><<<dim3(16, 32), 256, 0, stream>>>(oB, sa_wpt, sa_bp, stateF, ls2, stateF, 2048, 1024, 1024, 1024);

  // MLP
  add_ln_kernel<<<2048, 256, 0, stream>>>(stateF, nullptr, nullptr, lnB, n3_g, n3_b);
  gemm_kernel<3, 128, 128><<<dim3(32, 16), 256, 0, stream>>>(lnB, w1t, b1, nullptr, nullptr, hB, 2048, 4096, 1024, 1024);
  gemm_kernel<4, 128, 64><<<dim3(16, 16, 2), 256, 0, stream>>>(hB, w2t, nullptr, nullptr, nullptr, mlp2p, 2048, 1024, 2048, 4096);
  splitk_red_kernel<<<2048, 256, 0, stream>>>(mlp2p, b2, stateF, ls3, (float*)d_out);
}

// Round 19
// 276.918 us; speedup vs baseline: 1.0198x; 1.0198x over previous
//
#include <hip/hip_runtime.h>

#define DEV __device__ __forceinline__

typedef __bf16 bf16x8 __attribute__((ext_vector_type(8)));
typedef float f32x4 __attribute__((ext_vector_type(4)));

DEV unsigned short f2bf(float f) {
  __bf16 h = (__bf16)f;
  return __builtin_bit_cast(unsigned short, h);
}
DEV unsigned int cvtpk(float lo, float hi) {
  unsigned int r;
  asm("v_cvt_pk_bf16_f32 %0, %1, %2" : "=v"(r) : "v"(lo), "v"(hi));
  return r;
}

DEV void gload16(const void* g, void* l) {
  __builtin_amdgcn_global_load_lds(
      (const __attribute__((address_space(1))) unsigned int*)g,
      (__attribute__((address_space(3))) unsigned int*)l, 16, 0, 0);
}

// gelu via exp2: tanh(u) = 1 - 2/(exp2(u*2*log2e)+1)
DEV float gelu(float v) {
  const float u = 0.7978845608028654f * (v + 0.044715f * v * v * v);
  const float e = exp2f(u * 2.885390081777927f);
  return 0.5f * v * (2.f - 2.f / (e + 1.f));
}

// ---------- 64x64 transpose+convert; LDS tile provided by caller (>=16640B) ----------
DEV void tconv64_body(const float* __restrict__ W, unsigned short* __restrict__ Wt,
                      int K, int N, int bx, int by, float* tile /* [64][65] */) {
  const int t = threadIdx.x;
  const int rr = t >> 4;
  const int cc = (t & 15) * 4;
#pragma unroll
  for (int it = 0; it < 4; it++) {
    float4 v = *reinterpret_cast<const float4*>(
        &W[(size_t)(by * 64 + it * 16 + rr) * N + bx * 64 + cc]);
    tile[(it * 16 + rr) * 65 + cc] = v.x;
    tile[(it * 16 + rr) * 65 + cc + 1] = v.y;
    tile[(it * 16 + rr) * 65 + cc + 2] = v.z;
    tile[(it * 16 + rr) * 65 + cc + 3] = v.w;
  }
  __syncthreads();
  const int nr = t >> 3;
  const int kc = (t & 7) * 8;
#pragma unroll
  for (int it = 0; it < 2; it++) {
    const int n = it * 32 + nr;
    uint4 o;
    o.x = cvtpk(tile[(kc + 0) * 65 + n], tile[(kc + 1) * 65 + n]);
    o.y = cvtpk(tile[(kc + 2) * 65 + n], tile[(kc + 3) * 65 + n]);
    o.z = cvtpk(tile[(kc + 4) * 65 + n], tile[(kc + 5) * 65 + n]);
    o.w = cvtpk(tile[(kc + 6) * 65 + n], tile[(kc + 7) * 65 + n]);
    *reinterpret_cast<uint4*>(&Wt[(size_t)(bx * 64 + n) * K + by * 64 + kc]) = o;
  }
}

DEV void add_ln_body(const float* __restrict__ a, const float* b, float* x0_out,
                     unsigned short* __restrict__ y, const float* __restrict__ gam,
                     const float* __restrict__ bet, int row) {
  const int t = threadIdx.x;
  const int c = t * 4;
  const size_t base = (size_t)row * 1024 + c;
  float4 v = *reinterpret_cast<const float4*>(a + base);
  if (b) {
    float4 v2 = *reinterpret_cast<const float4*>(b + base);
    v.x += v2.x; v.y += v2.y; v.z += v2.z; v.w += v2.w;
  }
  if (x0_out) *reinterpret_cast<float4*>(x0_out + base) = v;
  float s = v.x + v.y + v.z + v.w;
  float sq = v.x * v.x + v.y * v.y + v.z * v.z + v.w * v.w;
#pragma unroll
  for (int o = 32; o > 0; o >>= 1) {
    s += __shfl_xor(s, o);
    sq += __shfl_xor(sq, o);
  }
  __shared__ float ps[4], pq[4];
  const int w = t >> 6;
  if ((t & 63) == 0) { ps[w] = s; pq[w] = sq; }
  __syncthreads();
  s = ps[0] + ps[1] + ps[2] + ps[3];
  sq = pq[0] + pq[1] + pq[2] + pq[3];
  const float mean = s * (1.f / 1024.f);
  const float var = sq * (1.f / 1024.f) - mean * mean;
  const float rstd = rsqrtf(var + 1e-5f);
  float4 gv = *reinterpret_cast<const float4*>(gam + c);
  float4 bv = *reinterpret_cast<const float4*>(bet + c);
  uint2 o2;
  o2.x = cvtpk((v.x - mean) * rstd * gv.x + bv.x, (v.y - mean) * rstd * gv.y + bv.y);
  o2.y = cvtpk((v.z - mean) * rstd * gv.z + bv.z, (v.w - mean) * rstd * gv.w + bv.w);
  *reinterpret_cast<uint2*>(y + base) = o2;
}

// kvcast: 8 floats/thread -> one uint4 (16B) store per output buffer
DEV void kvcast_body8(const float* __restrict__ p, const float* __restrict__ pe,
                      unsigned short* __restrict__ kvo, unsigned short* __restrict__ po,
                      int bid) {
  const size_t i = ((size_t)bid * 256 + threadIdx.x) * 8;
  float4 a0 = *reinterpret_cast<const float4*>(p + i);
  float4 a1 = *reinterpret_cast<const float4*>(p + i + 4);
  float4 b0 = *reinterpret_cast<const float4*>(pe + i);
  float4 b1 = *reinterpret_cast<const float4*>(pe + i + 4);
  uint4 kv, pp;
  kv.x = cvtpk(a0.x + b0.x, a0.y + b0.y);
  kv.y = cvtpk(a0.z + b0.z, a0.w + b0.w);
  kv.z = cvtpk(a1.x + b1.x, a1.y + b1.y);
  kv.w = cvtpk(a1.z + b1.z, a1.w + b1.w);
  pp.x = cvtpk(a0.x, a0.y);
  pp.y = cvtpk(a0.z, a0.w);
  pp.z = cvtpk(a1.x, a1.y);
  pp.w = cvtpk(a1.z, a1.w);
  *reinterpret_cast<uint4*>(kvo + i) = kv;
  *reinterpret_cast<uint4*>(po + i) = pp;
}

// ---------- prelude: only what gemm3 depends on: kvcast | ca q/k/v tconv | add_ln1 ----------
struct Pre {
  const float* caw[3]; unsigned short* cad[3];
  const float* state; const float* squery; float* stateF; unsigned short* lnB;
  const float* n1_g; const float* n1_b;
  const float* patches; const float* ppe; unsigned short* kvB; unsigned short* patB;
};
__global__ __launch_bounds__(256) void prelude_kernel(Pre p) {
  __shared__ __align__(16) float tile[64 * 65];
  const int bid = blockIdx.x;
  if (bid < 4096) {
    kvcast_body8(p.patches, p.ppe, p.kvB, p.patB, bid);
  } else if (bid < 4864) {  // ca wq/wk/wv tconvs (256 blocks each)
    const int i = bid - 4096;
    const int m = i >> 8, wi = i & 255;
    tconv64_body(p.caw[m], p.cad[m], 1024, 1024, wi & 15, wi >> 4, tile);
  } else {  // add_ln1
    add_ln_body(p.state, p.squery, p.stateF, p.lnB, p.n1_g, p.n1_b, bid - 4864);
  }
}

// ---------- standalone add_ln (mid-network LNs) ----------
__global__ __launch_bounds__(256) void add_ln_kernel(
    const float* __restrict__ a, const float* b, float* x0_out,
    unsigned short* __restrict__ y, const float* __restrict__ gam,
    const float* __restrict__ bet) {
  add_ln_body(a, b, x0_out, y, gam, bet, blockIdx.x);
}

// ---------- XCD swizzle helper (m204 bijective) ----------
DEV void xcd_swizzle(int gx, int gy, int& bx, int& by, int& bz) {
  const int gxy = gx * gy;
  const int nwg = gxy * gridDim.z;
  const int orig = (blockIdx.z * gy + blockIdx.y) * gx + blockIdx.x;
  const int q = nwg >> 3, r = nwg & 7;
  const int xcd = orig & 7;
  int wgid = (xcd < r ? xcd * (q + 1) : r * (q + 1) + (xcd - r) * q) + (orig >> 3);
  bz = wgid / gxy;
  wgid -= bz * gxy;
  if (gy >= gx) { by = wgid / gx; bx = wgid - by * gx; }
  else          { bx = wgid / gy; by = wgid - bx * gy; }
}

// ---------- GEMM core: 2-buffer single-barrier loop (R8 structure) ----------
template <int BM, int BN>
DEV void gemm_core(const unsigned short* __restrict__ A,
                   const unsigned short* __restrict__ Bt,
                   unsigned short* As, unsigned short* Bs,
                   int brow, int bcol, int K, int lda, int koff,
                   f32x4 (&acc)[BM / 32][BN / 32]) {
  constexpr int WM = BM / 32, WN = BN / 32;
  const int t = threadIdx.x;
  const int lane = t & 63, w = t >> 6;
  const int wr = w >> 1, wc = w & 1;
  const int g = lane >> 4, lr = lane & 15;
  const int srow = lane >> 2, scol = (lane & 3) * 8;

  auto stage = [&](int buf, int k0) {
#pragma unroll
    for (int i = 0; i < BM / 64; i++) {
      const int r0 = (i * 4 + w) * 16;
      gload16(A + (size_t)(brow + r0 + srow) * lda + koff + k0 + scol,
              &As[buf * BM * 32 + r0 * 32]);
    }
#pragma unroll
    for (int i = 0; i < BN / 64; i++) {
      const int r0 = (i * 4 + w) * 16;
      gload16(Bt + (size_t)(bcol + r0 + srow) * lda + koff + k0 + scol,
              &Bs[buf * BN * 32 + r0 * 32]);
    }
  };

  stage(0, 0);
  const int nk = K / 32;
  int cur = 0;
  for (int kt = 0; kt < nk; kt++) {
    __syncthreads();
    if (kt + 1 < nk) stage(cur ^ 1, (kt + 1) * 32);
    bf16x8 af[WM], bfr[WN];
#pragma unroll
    for (int m = 0; m < WM; m++)
      af[m] = *reinterpret_cast<const bf16x8*>(
          &As[cur * BM * 32 + (wr * (BM / 2) + m * 16 + lr) * 32 + g * 8]);
#pragma unroll
    for (int n = 0; n < WN; n++)
      bfr[n] = *reinterpret_cast<const bf16x8*>(
          &Bs[cur * BN * 32 + (wc * (BN / 2) + n * 16 + lr) * 32 + g * 8]);
    __builtin_amdgcn_s_setprio(1);
#pragma unroll
    for (int m = 0; m < WM; m++)
#pragma unroll
      for (int n = 0; n < WN; n++)
        acc[m][n] = __builtin_amdgcn_mfma_f32_16x16x32_bf16(af[m], bfr[n], acc[m][n], 0, 0, 0);
    __builtin_amdgcn_s_setprio(0);
    cur ^= 1;
  }
}

// ---------- transposed-V epilogue: acc -> LDS (col-major) -> coalesced vT store ----------
template <int BM, int BN>
DEV void epilogue_vT(f32x4 (&acc)[BM / 32][BN / 32], unsigned short* smem,
                     unsigned short* __restrict__ vT, const float* __restrict__ bias,
                     int brow, int bcol, int vcol0, int vNk, int rpb) {
  constexpr int WM = BM / 32, WN = BN / 32;
  constexpr int LDT = 136;
  const int t = threadIdx.x, lane = t & 63, w = t >> 6;
  const int wr = w >> 1, wc = w & 1;
  const int g = lane >> 4, lr = lane & 15;
  __syncthreads();
#pragma unroll
  for (int m = 0; m < WM; m++) {
    const int row0 = wr * (BM / 2) + m * 16 + g * 4;
#pragma unroll
    for (int n = 0; n < WN; n++) {
      const int cc = wc * (BN / 2) + n * 16 + lr;
      const float bv = bias[bcol + cc];
      uint2 pk;
      pk.x = cvtpk(acc[m][n][0] + bv, acc[m][n][1] + bv);
      pk.y = cvtpk(acc[m][n][2] + bv, acc[m][n][3] + bv);
      *reinterpret_cast<uint2*>(&smem[cc * LDT + row0]) = pk;
    }
  }
  __syncthreads();
  const int b = brow / rpb;
  const int kvb = brow % rpb;
  constexpr int ITERS = BM * BN / (256 * 8);
#pragma unroll
  for (int it = 0; it < ITERS; it++) {
    const int idx = it * 256 + t;
    const int cc = idx / (BM / 8);
    const int ch = idx % (BM / 8);
    const int dg = bcol + cc - vcol0;
    const int h = dg >> 6, d = dg & 63;
    uint4 v = *reinterpret_cast<uint4*>(&smem[cc * LDT + ch * 8]);
    *reinterpret_cast<uint4*>(
        &vT[((size_t)(b * 16 + h) * 64 + d) * vNk + kvb + ch * 8]) = v;
  }
}

// ---------- GEMM with epilogues ----------
// EPI 0: bf16 = acc+bias ; 2: f32 = resid+(acc+bias)*ls ; 3: bf16 = gelu(acc+bias)
// EPI 4: f32 partial = acc (split-K)
template <int EPI, int BM, int BN>
__global__ __launch_bounds__(256) void gemm_kernel(
    const unsigned short* __restrict__ A, const unsigned short* __restrict__ Bt,
    const float* __restrict__ bias, const float* resid,
    const float* __restrict__ ls, void* outp, int M, int N, int K, int lda) {
  constexpr int WM = BM / 32;
  constexpr int WN = BN / 32;
  __shared__ __align__(16) unsigned short smem[2 * BM * 32 + 2 * BN * 32];
  unsigned short* As = smem;
  unsigned short* Bs = smem + 2 * BM * 32;
  const int t = threadIdx.x;
  const int lane = t & 63, w = t >> 6;
  const int wr = w >> 1, wc = w & 1;
  const int g = lane >> 4, lr = lane & 15;

  int bx, by, bz;
  xcd_swizzle(gridDim.x, gridDim.y, bx, by, bz);
  const int brow = by * BM, bcol = bx * BN;

  f32x4 acc[WM][WN] = {};
  gemm_core<BM, BN>(A, Bt, As, Bs, brow, bcol, K, lda, bz * K, acc);

#pragma unroll
  for (int m = 0; m < WM; m++) {
    const int row0 = brow + wr * (BM / 2) + m * 16 + g * 4;
#pragma unroll
    for (int n = 0; n < WN; n++) {
      const int col = bcol + wc * (BN / 2) + n * 16 + lr;
      const float bv = (EPI == 4) ? 0.f : bias[col];
#pragma unroll
      for (int r = 0; r < 4; r++) {
        const float v = acc[m][n][r] + bv;
        const size_t idx = (size_t)(row0 + r) * N + col;
        if (EPI == 0) {
          ((unsigned short*)outp)[idx] = f2bf(v);
        } else if (EPI == 2) {
          ((float*)outp)[idx] = resid[idx] + v * ls[col];
        } else if (EPI == 3) {
          ((unsigned short*)outp)[idx] = f2bf(gelu(v));
        } else {
          ((float*)outp)[(size_t)bz * M * N + idx] = v;
        }
      }
    }
  }
}

// ---------- packed gemm3: GEMM blocks 0..1151 first; aux tail = deps of next dispatches ----------
struct G3X {
  const unsigned short* A[3]; const unsigned short* Bt[3];
  const float* bias[3]; unsigned short* out[3]; int ecum[3];
  unsigned short* vT; int vNk; int rpb;
  const float* wp; unsigned short* wpt;
  const float* saw[4]; unsigned short* sad[4];
  const float* bq; const float* bk; const float* bv; float* bqkv;
};
__global__ __launch_bounds__(256) void gemm3_kernel(G3X p, int N, int K) {
  constexpr int BM = 128, BN = 128, WM = BM / 32, WN = BN / 32;
  constexpr int STG = 2 * BM * 32 + 2 * BN * 32;
  constexpr int TRN = BN * 136;
  constexpr int SME = (TRN > STG) ? TRN : STG;  // 17408 shorts = 34816 B
  constexpr int NG = 1152;  // GEMM blocks (dense, dispatched first)
  __shared__ __align__(16) unsigned short smem[SME];
  const int bid = blockIdx.x;
  const int t = threadIdx.x;

  if (bid >= NG) {  // ---- aux tail: ca_wp + sa x4 transposes + cat3 (1292 blocks) ----
    float* tile = reinterpret_cast<float*>(smem);
    int i = bid - NG;
    if (i < 256) {
      tconv64_body(p.wp, p.wpt, 1024, 1024, i & 15, i >> 4, tile);
    } else if (i < 1280) {
      i -= 256;
      const int m = i >> 8, wi = i & 255;
      tconv64_body(p.saw[m], p.sad[m], 1024, 1024, wi & 15, wi >> 4, tile);
    } else {
      const int j = (i - 1280) * 256 + t;
      p.bqkv[j] = j < 1024 ? p.bq[j] : (j < 2048 ? p.bk[j - 1024] : p.bv[j - 2048]);
    }
    return;
  }

  // ---- GEMM range: bijective XCD swizzle over the 1152 GEMM blocks ----
  unsigned short* As = smem;
  unsigned short* Bs = smem + 2 * BM * 32;
  const int lane = t & 63, w = t >> 6;
  const int wr = w >> 1, wc = w & 1;
  const int g = lane >> 4, lr = lane & 15;
  const int wgid = (bid & 7) * (NG >> 3) + (bid >> 3);  // NG % 8 == 0
  const int by = wgid >> 3, bx = wgid & 7;              // gx=8, gy=144 (tall)
  const int s = (by >= p.ecum[0]) + (by >= p.ecum[1]);
  const int byloc = by - (s ? p.ecum[s - 1] : 0);
  const unsigned short* A = p.A[s];
  const unsigned short* Bt = p.Bt[s];
  const float* bias = p.bias[s];
  const int brow = byloc * BM, bcol = bx * BN;

  f32x4 acc[WM][WN] = {};
  gemm_core<BM, BN>(A, Bt, As, Bs, brow, bcol, K, K, 0, acc);

  if (s == 2) {
    epilogue_vT<BM, BN>(acc, smem, p.vT, bias, brow, bcol, 0, p.vNk, p.rpb);
    return;
  }
  unsigned short* outp = p.out[s];
#pragma unroll
  for (int m = 0; m < WM; m++) {
    const int row0 = brow + wr * (BM / 2) + m * 16 + g * 4;
#pragma unroll
    for (int n = 0; n < WN; n++) {
      const int col = bcol + wc * (BN / 2) + n * 16 + lr;
      const float bv = bias[col];
#pragma unroll
      for (int r = 0; r < 4; r++)
        outp[(size_t)(row0 + r) * N + col] = f2bf(acc[m][n][r] + bv);
    }
  }
}

// ---------- packed saQKV: EPI5 GEMM (768 blocks) + w1/w2 transpose tail (2048) ----------
struct G5X {
  const unsigned short* A; const unsigned short* Bt;
  const float* bias; unsigned short* out;
  unsigned short* vT; int vcol0; int vNk; int rpb;
  const float* w1; unsigned short* w1t;
  const float* w2; unsigned short* w2t;
};
__global__ __launch_bounds__(256) void gemm5x_kernel(G5X p, int M, int N, int K) {
  constexpr int BM = 128, BN = 64, WM = BM / 32, WN = BN / 32;
  constexpr int STG = 2 * BM * 32 + 2 * BN * 32;  // 12288 shorts = 24576B >= 16640B tile
  __shared__ __align__(16) unsigned short smem[STG];
  constexpr int NG = 768;
  const int bid = blockIdx.x;
  const int t = threadIdx.x;

  if (bid >= NG) {  // ---- aux tail: w1 / w2 transposes ----
    float* tile = reinterpret_cast<float*>(smem);
    int i = bid - NG;
    if (i < 1024) {
      tconv64_body(p.w1, p.w1t, 1024, 4096, i & 63, i >> 6, tile);
    } else {
      i -= 1024;
      tconv64_body(p.w2, p.w2t, 4096, 1024, i & 15, i >> 4, tile);
    }
    return;
  }

  unsigned short* As = smem;
  unsigned short* Bs = smem + 2 * BM * 32;
  const int lane = t & 63, w = t >> 6;
  const int wr = w >> 1, wc = w & 1;
  const int g = lane >> 4, lr = lane & 15;
  const int wgid = (bid & 7) * (NG >> 3) + (bid >> 3);  // bijective XCD swizzle
  const int bx = wgid >> 4, by = wgid & 15;             // gx=48 > gy=16: col-panels contiguous
  const int brow = by * BM, bcol = bx * BN;

  f32x4 acc[WM][WN] = {};
  gemm_core<BM, BN>(p.A, p.Bt, As, Bs, brow, bcol, K, K, 0, acc);

  if (bcol >= p.vcol0) {
    epilogue_vT<BM, BN>(acc, smem, p.vT, p.bias, brow, bcol, p.vcol0, p.vNk, p.rpb);
    return;
  }
#pragma unroll
  for (int m = 0; m < WM; m++) {
    const int row0 = brow + wr * (BM / 2) + m * 16 + g * 4;
#pragma unroll
    for (int n = 0; n < WN; n++) {
      const int col = bcol + wc * (BN / 2) + n * 16 + lr;
      const float bv = p.bias[col];
#pragma unroll
      for (int r = 0; r < 4; r++)
        p.out[(size_t)(row0 + r) * N + col] = f2bf(acc[m][n][r] + bv);
    }
  }
}

// ---------- split-K reduce + epilogue: out = resid + (p0+p1+bias)*ls ----------
__global__ __launch_bounds__(256) void splitk_red_kernel(
    const float* __restrict__ p, const float* __restrict__ bias,
    const float* __restrict__ resid, const float* __restrict__ ls,
    float* __restrict__ out) {
  const size_t i = ((size_t)blockIdx.x * 256 + threadIdx.x) * 4;
  const int c = (int)(i & 1023);
  float4 a = *reinterpret_cast<const float4*>(p + i);
  float4 b = *reinterpret_cast<const float4*>(p + 2048ull * 1024 + i);
  float4 rv = *reinterpret_cast<const float4*>(resid + i);
  float4 bb = *reinterpret_cast<const float4*>(bias + c);
  float4 lv = *reinterpret_cast<const float4*>(ls + c);
  float4 o;
  o.x = rv.x + (a.x + b.x + bb.x) * lv.x;
  o.y = rv.y + (a.y + b.y + bb.y) * lv.y;
  o.z = rv.z + (a.z + b.z + bb.z) * lv.z;
  o.w = rv.w + (a.w + b.w + bb.w) * lv.w;
  *reinterpret_cast<float4*>(out + i) = o;
}

// ---------- flash attention: 8 waves, QBLK=128, KVBLK=128, Q in regs ----------
__global__ __launch_bounds__(512) void attn_kernel(
    const unsigned short* __restrict__ Q, const unsigned short* __restrict__ Kp,
    const unsigned short* __restrict__ vT, unsigned short* __restrict__ O,
    int RSq, int RSk, int Nq, int Nk, float k2) {
  __shared__ __align__(16) unsigned short Ks[2][128 * 72];
  __shared__ __align__(16) unsigned short Vs[2][64 * 136];
  __shared__ __align__(16) unsigned short Ps[128 * 136];
  const int t = threadIdx.x, lane = t & 63, w = t >> 6;
  const int qt = blockIdx.y, h = blockIdx.x & 15, b = blockIdx.x >> 4;
  const int g = lane >> 4, lr = lane & 15;
  const int ksrow = t >> 2, kscol = (t & 3) * 16;
  const int vsrow = t >> 3, vscol = (t & 7) * 16;

  uint4 qr[2];
  {
    const unsigned short* qp = Q + (size_t)(b * Nq + qt * 128 + w * 16 + lr) * RSq + h * 64 + g * 8;
    qr[0] = *reinterpret_cast<const uint4*>(qp);
    qr[1] = *reinterpret_cast<const uint4*>(qp + 32);
  }
  float m_i = -1e30f, l_i = 0.f;
  f32x4 acc_o[4] = {};

  auto kaddr = [&](int kv0) {
    return reinterpret_cast<const uint4*>(
        Kp + (size_t)(b * Nk + kv0 + ksrow) * RSk + h * 64 + kscol);
  };
  auto vaddr = [&](int kv0) {
    return reinterpret_cast<const uint4*>(
        vT + ((size_t)(b * 16 + h) * 64 + vsrow) * Nk + kv0 + vscol);
  };

  uint4 kr0 = kaddr(0)[0], kr1 = kaddr(0)[1];
  uint4 vr0 = vaddr(0)[0], vr1 = vaddr(0)[1];

  int cur = 0;
  for (int kv0 = 0; kv0 < Nk; kv0 += 128) {
    *reinterpret_cast<uint4*>(&Ks[cur][ksrow * 72 + kscol]) = kr0;
    *reinterpret_cast<uint4*>(&Ks[cur][ksrow * 72 + kscol + 8]) = kr1;
    *reinterpret_cast<uint4*>(&Vs[cur][vsrow * 136 + vscol]) = vr0;
    *reinterpret_cast<uint4*>(&Vs[cur][vsrow * 136 + vscol + 8]) = vr1;
    __syncthreads();
    if (kv0 + 128 < Nk) {
      kr0 = kaddr(kv0 + 128)[0]; kr1 = kaddr(kv0 + 128)[1];
      vr0 = vaddr(kv0 + 128)[0]; vr1 = vaddr(kv0 + 128)[1];
    }

    f32x4 accs[8] = {};
    __builtin_amdgcn_s_setprio(1);
#pragma unroll
    for (int d0 = 0; d0 < 64; d0 += 32) {
      bf16x8 qf = __builtin_bit_cast(bf16x8, qr[d0 >> 5]);
#pragma unroll
      for (int m = 0; m < 8; m++) {
        bf16x8 kf = *reinterpret_cast<const bf16x8*>(&Ks[cur][(m * 16 + lr) * 72 + d0 + g * 8]);
        accs[m] = __builtin_amdgcn_mfma_f32_16x16x32_bf16(kf, qf, accs[m], 0, 0, 0);
      }
    }
    __builtin_amdgcn_s_setprio(0);
    float pmax = -1e30f;
#pragma unroll
    for (int m = 0; m < 8; m++)
#pragma unroll
      for (int r = 0; r < 4; r++) pmax = fmaxf(pmax, accs[m][r]);
    pmax = fmaxf(pmax, __shfl_xor(pmax, 16));
    pmax = fmaxf(pmax, __shfl_xor(pmax, 32));
    const float pm2 = pmax * k2;
    if (!__all(pm2 <= m_i + 8.f)) {
      const float m_new = fmaxf(m_i, pm2);
      const float corr = exp2f(m_i - m_new);
      m_i = m_new;
      l_i *= corr;
#pragma unroll
      for (int r = 0; r < 4; r++) {
        const float cf = __shfl(corr, g * 4 + r);
#pragma unroll
        for (int n = 0; n < 4; n++) acc_o[n][r] *= cf;
      }
    }
    float psum = 0.f;
#pragma unroll
    for (int m = 0; m < 8; m++) {
      float p0 = exp2f(fmaf(accs[m][0], k2, -m_i));
      float p1 = exp2f(fmaf(accs[m][1], k2, -m_i));
      float p2 = exp2f(fmaf(accs[m][2], k2, -m_i));
      float p3 = exp2f(fmaf(accs[m][3], k2, -m_i));
      psum += p0 + p1 + p2 + p3;
      uint2 pk;
      pk.x = cvtpk(p0, p1);
      pk.y = cvtpk(p2, p3);
      *reinterpret_cast<uint2*>(&Ps[(w * 16 + lr) * 136 + m * 16 + g * 4]) = pk;
    }
    psum += __shfl_xor(psum, 16);
    psum += __shfl_xor(psum, 32);
    l_i += psum;
    __builtin_amdgcn_s_setprio(1);
#pragma unroll
    for (int ks = 0; ks < 4; ks++) {
      bf16x8 pf = *reinterpret_cast<const bf16x8*>(&Ps[(w * 16 + lr) * 136 + ks * 32 + g * 8]);
#pragma unroll
      for (int n = 0; n < 4; n++) {
        bf16x8 vf = *reinterpret_cast<const bf16x8*>(&Vs[cur][(n * 16 + lr) * 136 + ks * 32 + g * 8]);
        acc_o[n] = __builtin_amdgcn_mfma_f32_16x16x32_bf16(pf, vf, acc_o[n], 0, 0, 0);
      }
    }
    __builtin_amdgcn_s_setprio(0);
    cur ^= 1;
  }
#pragma unroll
  for (int r = 0; r < 4; r++) {
    const float li = __shfl(l_i, g * 4 + r);
    const float inv = 1.f / li;
    const int qrow = qt * 128 + w * 16 + g * 4 + r;
#pragma unroll
    for (int n = 0; n < 4; n++)
      O[(size_t)(b * Nq + qrow) * 1024 + h * 64 + n * 16 + lr] = f2bf(acc_o[n][r] * inv);
  }
}

extern "C" void kernel_launch(void* const* d_in, const int* in_sizes, int n_in,
                              void* d_out, int out_size, void* d_ws, size_t ws_size,
                              hipStream_t stream) {
  const float* state = (const float*)d_in[0];
  const float* patches = (const float*)d_in[1];
  const float* ppe = (const float*)d_in[2];
  const float* squery = (const float*)d_in[3];
  const float* ca_wq = (const float*)d_in[4];
  const float* ca_bq = (const float*)d_in[5];
  const float* ca_wk = (const float*)d_in[6];
  const float* ca_bk = (const float*)d_in[7];
  const float* ca_wv = (const float*)d_in[8];
  const float* ca_bv = (const float*)d_in[9];
  const float* ca_wp = (const float*)d_in[10];
  const float* ca_bp = (const float*)d_in[11];
  const float* sa_wq = (const float*)d_in[12];
  const float* sa_bq = (const float*)d_in[13];
  const float* sa_wk = (const float*)d_in[14];
  const float* sa_bk = (const float*)d_in[15];
  const float* sa_wv = (const float*)d_in[16];
  const float* sa_bv = (const float*)d_in[17];
  const float* sa_wp = (const float*)d_in[18];
  const float* sa_bp = (const float*)d_in[19];
  const float* w1 = (const float*)d_in[20];
  const float* b1 = (const float*)d_in[21];
  const float* w2 = (const float*)d_in[22];
  const float* b2 = (const float*)d_in[23];
  const float* n1_g = (const float*)d_in[24];
  const float* n1_b = (const float*)d_in[25];
  const float* ls1 = (const float*)d_in[26];
  const float* n2_g = (const float*)d_in[27];
  const float* n2_b = (const float*)d_in[28];
  const float* ls2 = (const float*)d_in[29];
  const float* n3_g = (const float*)d_in[30];
  const float* n3_b = (const float*)d_in[31];
  const float* ls3 = (const float*)d_in[32];

  char* wsp = (char*)d_ws;
  auto alloc = [&](size_t bytes) {
    void* p = (void*)wsp;
    wsp += (bytes + 255) & ~(size_t)255;
    return p;
  };
  float* stateF = (float*)alloc(2048ull * 1024 * 4);
  unsigned short* lnB = (unsigned short*)alloc(2048ull * 1024 * 2);
  unsigned short* kvB = (unsigned short*)alloc(8192ull * 1024 * 2);
  unsigned short* patB = (unsigned short*)alloc(8192ull * 1024 * 2);
  unsigned short* qB = (unsigned short*)alloc(2048ull * 1024 * 2);
  unsigned short* kB = (unsigned short*)alloc(8192ull * 1024 * 2);
  unsigned short* vB = (unsigned short*)alloc(8192ull * 1024 * 2);
  unsigned short* oB = (unsigned short*)alloc(2048ull * 1024 * 2);
  unsigned short* hB = kvB;    // kvB dead after gemm3
  unsigned short* qkvB = kB;   // kB dead after cross attention
  unsigned short* vTc = vB;    // cross V written transposed directly here
  unsigned short* vTs = qB;    // qB dead after cross attention
  float* mlp2p = (float*)patB; // patB dead after gemm3
  unsigned short* ca_wqt = (unsigned short*)alloc(1024ull * 1024 * 2);
  unsigned short* ca_wkt = (unsigned short*)alloc(1024ull * 1024 * 2);
  unsigned short* ca_wvt = (unsigned short*)alloc(1024ull * 1024 * 2);
  unsigned short* ca_wpt = (unsigned short*)alloc(1024ull * 1024 * 2);
  unsigned short* sa_wqkvt = (unsigned short*)alloc(3072ull * 1024 * 2);
  unsigned short* sa_wpt = (unsigned short*)alloc(1024ull * 1024 * 2);
  unsigned short* w1t = (unsigned short*)alloc(4096ull * 1024 * 2);
  unsigned short* w2t = (unsigned short*)alloc(4096ull * 1024 * 2);
  float* sa_bqkv = (float*)alloc(3072 * 4);

  // ---- prelude: only gemm3's dependencies ----
  Pre pre;
  pre.caw[0] = ca_wq; pre.cad[0] = ca_wqt;
  pre.caw[1] = ca_wk; pre.cad[1] = ca_wkt;
  pre.caw[2] = ca_wv; pre.cad[2] = ca_wvt;
  pre.state = state; pre.squery = squery; pre.stateF = stateF; pre.lnB = lnB;
  pre.n1_g = n1_g; pre.n1_b = n1_b;
  pre.patches = patches; pre.ppe = ppe; pre.kvB = kvB; pre.patB = patB;
  prelude_kernel<<<6912, 256, 0, stream>>>(pre);

  const float k2 = 0.125f * 1.4426950408889634f;  // 64^-0.5 * log2(e)

  // packed gemm3: q/k/v projections (0..1151) + tail {ca_wp, sa x4, cat3} (1292)
  G3X g3;
  g3.A[0] = lnB;  g3.Bt[0] = ca_wqt; g3.bias[0] = ca_bq; g3.out[0] = qB;      g3.ecum[0] = 16;
  g3.A[1] = kvB;  g3.Bt[1] = ca_wkt; g3.bias[1] = ca_bk; g3.out[1] = kB;      g3.ecum[1] = 80;
  g3.A[2] = patB; g3.Bt[2] = ca_wvt; g3.bias[2] = ca_bv; g3.out[2] = nullptr; g3.ecum[2] = 144;
  g3.vT = vTc; g3.vNk = 2048; g3.rpb = 2048;
  g3.wp = ca_wp; g3.wpt = ca_wpt;
  g3.saw[0] = sa_wq; g3.sad[0] = sa_wqkvt;
  g3.saw[1] = sa_wk; g3.sad[1] = sa_wqkvt + 1024ull * 1024;
  g3.saw[2] = sa_wv; g3.sad[2] = sa_wqkvt + 2048ull * 1024;
  g3.saw[3] = sa_wp; g3.sad[3] = sa_wpt;
  g3.bq = sa_bq; g3.bk = sa_bk; g3.bv = sa_bv; g3.bqkv = sa_bqkv;
  gemm3_kernel<<<2444, 256, 0, stream>>>(g3, 1024, 1024);
  attn_kernel<<<dim3(64, 4), 512, 0, stream>>>(qB, kB, vTc, oB, 1024, 1024, 512, 2048, k2);
  gemm_kernel<2, 64, 64><<<dim3(16, 32), 256, 0, stream>>>(oB, ca_wpt, ca_bp, stateF, ls1, stateF, 2048, 1024, 1024, 1024);

  // self-attn: packed QKV projection (768 GEMM blocks) + w1/w2 transpose tail (2048)
  add_ln_kernel<<<2048, 256, 0, stream>>>(stateF, nullptr, nullptr, lnB, n2_g, n2_b);
  G5X g5;
  g5.A = lnB; g5.Bt = sa_wqkvt; g5.bias = sa_bqkv; g5.out = qkvB;
  g5.vT = vTs; g5.vcol0 = 2048; g5.vNk = 512; g5.rpb = 512;
  g5.w1 = w1; g5.w1t = w1t; g5.w2 = w2; g5.w2t = w2t;
  gemm5x_kernel<<<2816, 256, 0, stream>>>(g5, 2048, 3072, 1024);
  attn_kernel<<<dim3(64, 4), 512, 0, stream>>>(qkvB, qkvB + 1024, vTs, oB, 3072, 3072, 512, 512, k2);
  gemm_kernel<2, 64, 64><<<dim3(16, 32), 256, 0, stream>>>(oB, sa_wpt, sa_bp, stateF, ls2, stateF, 2048, 1024, 1024, 1024);

  // MLP
  add_ln_kernel<<<2048, 256, 0, stream>>>(stateF, nullptr, nullptr, lnB, n3_g, n3_b);
  gemm_kernel<3, 128, 128><<<dim3(32, 16), 256, 0, stream>>>(lnB, w1t, b1, nullptr, nullptr, hB, 2048, 4096, 1024, 1024);
  gemm_kernel<4, 128, 64><<<dim3(16, 16, 2), 256, 0, stream>>>(hB, w2t, nullptr, nullptr, nullptr, mlp2p, 2048, 1024, 2048, 4096);
  splitk_red_kernel<<<2048, 256, 0, stream>>>(mlp2p, b2, stateF, ls3, (float*)d_out);
}